// Round 3
// baseline (988.151 us; speedup 1.0000x reference)
//
#include <hip/hip_runtime.h>

typedef __attribute__((ext_vector_type(8))) short bf16x8;
typedef __attribute__((ext_vector_type(4))) float f32x4;

__device__ __forceinline__ short f2b(float f) {
  unsigned u = __builtin_bit_cast(unsigned, f);
  unsigned r = (u + 0x7FFFu + ((u >> 16) & 1u)) >> 16;
  return (short)r;
}
__device__ __forceinline__ float b2f(short s) {
  unsigned u = ((unsigned)(unsigned short)s) << 16;
  return __builtin_bit_cast(float, u);
}

__device__ __forceinline__ void gload16(const void* g, void* l) {
  __builtin_amdgcn_global_load_lds(
      (const __attribute__((address_space(1))) void*)g,
      (__attribute__((address_space(3))) void*)l, 16, 0, 0);
}

// ---------------- packing kernels ----------------
__global__ void cvt_bf16_vec(const float* __restrict__ src, short* __restrict__ dst, long n) {
  long i = ((long)blockIdx.x * 256 + threadIdx.x) * 8;
  if (i >= n) return;
  f32x4 a = *(const f32x4*)(src + i);
  f32x4 b = *(const f32x4*)(src + i + 4);
  bf16x8 o;
#pragma unroll
  for (int j = 0; j < 4; j++) o[j] = f2b(a[j]);
#pragma unroll
  for (int j = 0; j < 4; j++) o[j + 4] = f2b(b[j]);
  *(bf16x8*)(dst + i) = o;
}

// dst[n*K + k] = bf16(src[k*N + n]);  K = 1<<kbits
__global__ void transpose_cvt(const float* __restrict__ src, short* __restrict__ dst,
                              int kbits, int N) {
  long t = (long)blockIdx.x * 256 + threadIdx.x;
  int K = 1 << kbits;
  if (t >= (long)K * N) return;
  int k = (int)(t & (K - 1));
  int n = (int)(t >> kbits);
  dst[t] = f2b(src[(long)k * N + n]);
}

__global__ void pack_bias3(const float* __restrict__ b0, const float* __restrict__ b1,
                           const float* __restrict__ b2, float* __restrict__ out) {
  int t = blockIdx.x * 256 + threadIdx.x;
  if (t >= 1536) return;
  out[t] = (t < 512) ? b0[t] : ((t < 1024) ? b1[t - 512] : b2[t - 1024]);
}

// ---------------- 256x256 GEMM, BK=32, 4-buffer LDS ring, counted vmcnt ----
// C = A[M][K] @ Bt[N][K]^T (bf16 in). Epilogues as before.
// 512 threads = 8 waves (2 M x 4 N); per-wave output 128x64.
// LDS: 4 ring buffers x (A 16KB + B 16KB) = 128 KiB.
// Swizzle: 16B-chunk index c4' = c4 ^ ((row>>1)&3); write side via pre-swizzled
// global source (linear gload_lds dest), read side via same XOR -> 2-way banks.
template <int EPI>
__global__ __launch_bounds__(512, 2) void gemm256(
    const short* __restrict__ A, const short* __restrict__ Bt,
    const float* __restrict__ bias, const float* __restrict__ resF,
    const short* __restrict__ resB, void* __restrict__ Cout,
    int K, int ldc, int gxN) {
  __shared__ char lds[131072];
  const int t = threadIdx.x;
  const int w = t >> 6, lane = t & 63;
  const int lr = lane & 15, lg = lane >> 4;
  const int wm = w >> 2, wn = w & 3;

  // XCD-bijective block swizzle (m204), n-fastest tile order
  const int nwg = gridDim.x;
  const int orig = blockIdx.x;
  const int q = nwg >> 3, r = nwg & 7, xcd = orig & 7, idx = orig >> 3;
  const int swz = (xcd < r ? xcd * (q + 1) : r * (q + 1) + (xcd - r) * q) + idx;
  const long m0 = (long)(swz / gxN) * 256;
  const int n0 = (swz % gxN) * 256;

  const int NKT = K >> 5;

  // staging: thread t covers (row = l*128 + t>>2, chunk c4 = t&3) of each
  // half; pre-swizzled source chunk = (t&3) ^ ((t>>3)&3).
  const int srow = t >> 2;
  const int schunk = (t & 3) ^ ((t >> 3) & 3);
  const short* sA = A + (m0 + srow) * (long)K + schunk * 8;
  const short* sB = Bt + ((long)n0 + srow) * K + schunk * 8;
  const long sOff1 = (long)128 * K;  // second half (l=1)
  const int dst0 = t * 16;

#define STAGE_A(kt)                                                        \
  {                                                                        \
    char* d = lds + ((kt) & 3) * 32768 + dst0;                             \
    gload16(sA + (long)(kt) * 32, d);                                      \
    gload16(sA + sOff1 + (long)(kt) * 32, d + 8192);                       \
  }
#define STAGE_B(kt)                                                        \
  {                                                                        \
    char* d = lds + ((kt) & 3) * 32768 + 16384 + dst0;                     \
    gload16(sB + (long)(kt) * 32, d);                                      \
    gload16(sB + sOff1 + (long)(kt) * 32, d + 8192);                       \
  }

  // fragment read offsets (swizzled chunk)
  const int colSw = (lg ^ ((lr >> 1) & 3)) * 16;
  const int aBase = wm * 8192 + lr * 64 + colSw;          // + mi*1024
  const int bBase = 16384 + wn * 4096 + lr * 64 + colSw;  // + nj*1024

  f32x4 acc[8][4];
#pragma unroll
  for (int i = 0; i < 8; i++)
#pragma unroll
    for (int j = 0; j < 4; j++) acc[i][j] = f32x4{0.f, 0.f, 0.f, 0.f};

  // prologue: stage tiles 0,1,2 (NKT >= 16 always here)
  STAGE_A(0) STAGE_B(0) STAGE_A(1) STAGE_B(1) STAGE_A(2) STAGE_B(2)

  for (int kt = 0; kt < NKT; ++kt) {
    const char* Lb = lds + (kt & 3) * 32768;
    // own 4 loads of tile kt are older than the newest 8 (kt+1, kt+2)
    asm volatile("s_waitcnt vmcnt(8)\n\ts_barrier" ::: "memory");
    bf16x8 bfr[4], afr[4];
#pragma unroll
    for (int nj = 0; nj < 4; nj++) bfr[nj] = *(const bf16x8*)(Lb + bBase + nj * 1024);
#pragma unroll
    for (int mi = 0; mi < 4; mi++) afr[mi] = *(const bf16x8*)(Lb + aBase + mi * 1024);
    if (kt + 3 < NKT) STAGE_A(kt + 3)
    __builtin_amdgcn_s_setprio(1);
#pragma unroll
    for (int mi = 0; mi < 4; mi++)
#pragma unroll
      for (int nj = 0; nj < 4; nj++)
        acc[mi][nj] =
            __builtin_amdgcn_mfma_f32_16x16x32_bf16(afr[mi], bfr[nj], acc[mi][nj], 0, 0, 0);
    __builtin_amdgcn_s_setprio(0);
    asm volatile("s_barrier" ::: "memory");
#pragma unroll
    for (int mi = 0; mi < 4; mi++)
      afr[mi] = *(const bf16x8*)(Lb + aBase + 4096 + mi * 1024);
    if (kt + 3 < NKT) STAGE_B(kt + 3)
    __builtin_amdgcn_s_setprio(1);
#pragma unroll
    for (int mi = 0; mi < 4; mi++)
#pragma unroll
      for (int nj = 0; nj < 4; nj++)
        acc[mi + 4][nj] = __builtin_amdgcn_mfma_f32_16x16x32_bf16(afr[mi], bfr[nj],
                                                                  acc[mi + 4][nj], 0, 0, 0);
    __builtin_amdgcn_s_setprio(0);
  }
#undef STAGE_A
#undef STAGE_B

  // epilogue
#pragma unroll
  for (int mi = 0; mi < 8; mi++)
#pragma unroll
    for (int nj = 0; nj < 4; nj++)
#pragma unroll
      for (int i = 0; i < 4; i++) {
        long row = m0 + wm * 128 + mi * 16 + lg * 4 + i;
        int col = n0 + wn * 64 + nj * 16 + lr;
        float v = acc[mi][nj][i] + bias[col];
        if (EPI == 0) {
          ((short*)Cout)[row * ldc + col] = f2b(v);
        } else if (EPI == 1) {
          float gl = 0.5f * v * (1.f + erff(v * 0.70710678118654752f));
          ((short*)Cout)[row * ldc + col] = f2b(gl);
        } else if (EPI == 2) {
          ((float*)Cout)[row * ldc + col] = v + resF[row * ldc + col];
        } else {
          ((float*)Cout)[row * ldc + col] = v + b2f(resB[row * ldc + col]);
        }
      }
}

// ---------------- windowed attention ----------------
__global__ __launch_bounds__(256, 2) void attn_win(const short* __restrict__ QKV,
                                                   short* __restrict__ AO) {
  __shared__ short Vs[64 * 72];
  __shared__ short Ps[64 * 72];
  const int t = threadIdx.x, w = t >> 6, lane = t & 63;
  const int lr = lane & 15, lg = lane >> 4;
  const long base = (long)blockIdx.x * 64 * 1536;
  const long obase = (long)blockIdx.x * 64 * 512;

  for (int h = 0; h < 8; h++) {
    const int co = h * 64;
#pragma unroll
    for (int it = 0; it < 2; it++) {
      int c = t + it * 256;
      int j = c >> 3, d0 = (c & 7) * 8;
      *(bf16x8*)(Vs + j * 72 + d0) =
          *(const bf16x8*)(QKV + base + (long)j * 1536 + 1024 + co + d0);
    }
    __syncthreads();

    bf16x8 qf[2], kf[4][2];
#pragma unroll
    for (int kb = 0; kb < 2; kb++)
      qf[kb] = *(const bf16x8*)(QKV + base + (long)(w * 16 + lr) * 1536 + co + kb * 32 + lg * 8);
#pragma unroll
    for (int nj = 0; nj < 4; nj++)
#pragma unroll
      for (int kb = 0; kb < 2; kb++)
        kf[nj][kb] = *(const bf16x8*)(QKV + base + (long)(nj * 16 + lr) * 1536 + 512 + co +
                                      kb * 32 + lg * 8);

    f32x4 s[4];
#pragma unroll
    for (int nj = 0; nj < 4; nj++) {
      s[nj] = f32x4{0.f, 0.f, 0.f, 0.f};
      s[nj] = __builtin_amdgcn_mfma_f32_16x16x32_bf16(qf[0], kf[nj][0], s[nj], 0, 0, 0);
      s[nj] = __builtin_amdgcn_mfma_f32_16x16x32_bf16(qf[1], kf[nj][1], s[nj], 0, 0, 0);
      s[nj] = s[nj] * 0.125f;
    }

#pragma unroll
    for (int i = 0; i < 4; i++) {
      float mx = fmaxf(fmaxf(s[0][i], s[1][i]), fmaxf(s[2][i], s[3][i]));
#pragma unroll
      for (int off = 1; off < 16; off <<= 1) mx = fmaxf(mx, __shfl_xor(mx, off, 64));
      float sum = 0.f;
#pragma unroll
      for (int nj = 0; nj < 4; nj++) {
        float p = __expf(s[nj][i] - mx);
        s[nj][i] = p;
        sum += p;
      }
#pragma unroll
      for (int off = 1; off < 16; off <<= 1) sum += __shfl_xor(sum, off, 64);
      float inv = 1.f / sum;
#pragma unroll
      for (int nj = 0; nj < 4; nj++) s[nj][i] *= inv;
    }

#pragma unroll
    for (int nj = 0; nj < 4; nj++)
#pragma unroll
      for (int i = 0; i < 4; i++)
        Ps[(w * 16 + lg * 4 + i) * 72 + nj * 16 + lr] = f2b(s[nj][i]);

    bf16x8 pa[2];
#pragma unroll
    for (int kb = 0; kb < 2; kb++)
      pa[kb] = *(const bf16x8*)(Ps + (w * 16 + lr) * 72 + kb * 32 + lg * 8);

    f32x4 o[4];
#pragma unroll
    for (int nb = 0; nb < 4; nb++) o[nb] = f32x4{0.f, 0.f, 0.f, 0.f};
#pragma unroll
    for (int kb = 0; kb < 2; kb++)
#pragma unroll
      for (int nb = 0; nb < 4; nb++) {
        bf16x8 vb;
#pragma unroll
        for (int jj = 0; jj < 8; jj++)
          vb[jj] = Vs[(kb * 32 + lg * 8 + jj) * 72 + nb * 16 + lr];
        o[nb] = __builtin_amdgcn_mfma_f32_16x16x32_bf16(pa[kb], vb, o[nb], 0, 0, 0);
      }

#pragma unroll
    for (int nb = 0; nb < 4; nb++)
#pragma unroll
      for (int i = 0; i < 4; i++)
        AO[obase + (long)(w * 16 + lg * 4 + i) * 512 + co + nb * 16 + lr] = f2b(o[nb][i]);
    __syncthreads();
  }
}

// ---------------- LayerNorm over C=512, one row per wave ----------------
template <int OUTB>
__global__ __launch_bounds__(256, 4) void ln_rows(const float* __restrict__ Y,
                                                  const float* __restrict__ gamma,
                                                  const float* __restrict__ beta,
                                                  short* __restrict__ Hb,
                                                  float* __restrict__ Of) {
  const int w = threadIdx.x >> 6, lane = threadIdx.x & 63;
  const long row = (long)blockIdx.x * 4 + w;
  const float* y = Y + row * 512 + lane * 8;
  f32x4 a = *(const f32x4*)(y);
  f32x4 b = *(const f32x4*)(y + 4);
  float s = a[0] + a[1] + a[2] + a[3] + b[0] + b[1] + b[2] + b[3];
  float s2 = a[0] * a[0] + a[1] * a[1] + a[2] * a[2] + a[3] * a[3] + b[0] * b[0] +
             b[1] * b[1] + b[2] * b[2] + b[3] * b[3];
#pragma unroll
  for (int off = 1; off < 64; off <<= 1) {
    s += __shfl_xor(s, off, 64);
    s2 += __shfl_xor(s2, off, 64);
  }
  float mu = s * (1.f / 512.f);
  float var = s2 * (1.f / 512.f) - mu * mu;
  float rstd = rsqrtf(fmaxf(var, 0.f) + 1e-12f);
  const int c0 = lane * 8;
  f32x4 ga = *(const f32x4*)(gamma + c0), gb = *(const f32x4*)(gamma + c0 + 4);
  f32x4 ba = *(const f32x4*)(beta + c0), bb = *(const f32x4*)(beta + c0 + 4);
  if (OUTB) {
    bf16x8 o;
#pragma unroll
    for (int j = 0; j < 4; j++) o[j] = f2b(ga[j] * ((a[j] - mu) * rstd) + ba[j]);
#pragma unroll
    for (int j = 0; j < 4; j++) o[j + 4] = f2b(gb[j] * ((b[j] - mu) * rstd) + bb[j]);
    *(bf16x8*)(Hb + row * 512 + c0) = o;
  } else {
    f32x4 o0, o1;
#pragma unroll
    for (int j = 0; j < 4; j++) o0[j] = ga[j] * ((a[j] - mu) * rstd) + ba[j];
#pragma unroll
    for (int j = 0; j < 4; j++) o1[j] = gb[j] * ((b[j] - mu) * rstd) + bb[j];
    *(f32x4*)(Of + row * 512 + c0) = o0;
    *(f32x4*)(Of + row * 512 + c0 + 4) = o1;
  }
}

// ---------------- driver ----------------
extern "C" void kernel_launch(void* const* d_in, const int* in_sizes, int n_in,
                              void* d_out, int out_size, void* d_ws, size_t ws_size,
                              hipStream_t stream) {
  (void)in_sizes; (void)n_in; (void)out_size;
  const float* x = (const float*)d_in[0];
  const float* wq = (const float*)d_in[1];
  const float* bq = (const float*)d_in[2];
  const float* wk = (const float*)d_in[3];
  const float* bk = (const float*)d_in[4];
  const float* wv = (const float*)d_in[5];
  const float* bv = (const float*)d_in[6];
  const float* wo = (const float*)d_in[7];
  const float* bo = (const float*)d_in[8];
  const float* g1 = (const float*)d_in[9];
  const float* be1 = (const float*)d_in[10];
  const float* wfc1 = (const float*)d_in[11];
  const float* bfc1 = (const float*)d_in[12];
  const float* wfc2 = (const float*)d_in[13];
  const float* bfc2 = (const float*)d_in[14];
  const float* g2 = (const float*)d_in[15];
  const float* be2 = (const float*)d_in[16];

  const long T = 65536;
  char* ws = (char*)d_ws;

  // ---- weights at offset 0 (~6.3 MiB) ----
  short* WQKVT = (short*)(ws);                 // [1536][512]
  short* WOT = WQKVT + 1536 * 512;             // [512][512]
  short* WFC1T = WOT + 512 * 512;              // [2048][512]
  short* WFC2T = WFC1T + 2048 * 512;           // [512][2048]
  float* BQKV = (float*)(WFC2T + 512 * 2048);  // [1536]
  size_t woff = ((size_t)((char*)(BQKV + 1536) - ws) + 255) & ~(size_t)255;

  // ---- adaptive chunking (Tc multiple of 256) ----
  size_t avail = (ws_size > woff) ? (ws_size - woff) : 0;
  long Tc = T;
  while (Tc > 256 && (size_t)Tc * 7168 > avail) Tc >>= 1;
  const long nch = T / Tc;

  char* R0 = ws + woff;               // QKV bf16 [Tc][1536] / Y1 f32 / FF1 bf16 [Tc][2048]
  char* R1 = R0 + (size_t)Tc * 4096;  // XB bf16 / AO bf16 / Y2 f32
  char* R2 = R1 + (size_t)Tc * 2048;  // H bf16

  short* QKV = (short*)R0;
  float* Y1 = (float*)R0;
  short* FF1 = (short*)R0;
  short* XB = (short*)R1;
  short* AO = (short*)R1;
  float* Y2 = (float*)R1;
  short* H = (short*)R2;

  // ---- pack weights ----
  transpose_cvt<<<1024, 256, 0, stream>>>(wq, WQKVT, 9, 512);
  transpose_cvt<<<1024, 256, 0, stream>>>(wk, WQKVT + 512 * 512, 9, 512);
  transpose_cvt<<<1024, 256, 0, stream>>>(wv, WQKVT + 1024 * 512, 9, 512);
  transpose_cvt<<<1024, 256, 0, stream>>>(wo, WOT, 9, 512);
  transpose_cvt<<<4096, 256, 0, stream>>>(wfc1, WFC1T, 9, 2048);
  transpose_cvt<<<4096, 256, 0, stream>>>(wfc2, WFC2T, 11, 512);
  pack_bias3<<<6, 256, 0, stream>>>(bq, bk, bv, BQKV);

  for (long c = 0; c < nch; c++) {
    const long t0 = c * Tc;
    const int mb = (int)(Tc / 256);
    cvt_bf16_vec<<<(int)(Tc / 4), 256, 0, stream>>>(x + t0 * 512, XB, Tc * 512);
    gemm256<0><<<mb * 6, 512, 0, stream>>>(XB, WQKVT, BQKV, nullptr, nullptr,
                                           (void*)QKV, 512, 1536, 6);
    attn_win<<<(int)(Tc / 64), 256, 0, stream>>>(QKV, AO);
    gemm256<2><<<mb * 2, 512, 0, stream>>>(AO, WOT, bo, x + t0 * 512, nullptr,
                                           (void*)Y1, 512, 512, 2);
    ln_rows<1><<<(int)(Tc / 4), 256, 0, stream>>>(Y1, g1, be1, H, nullptr);
    gemm256<1><<<mb * 8, 512, 0, stream>>>(H, WFC1T, bfc1, nullptr, nullptr,
                                           (void*)FF1, 512, 2048, 8);
    gemm256<3><<<mb * 2, 512, 0, stream>>>(FF1, WFC2T, bfc2, nullptr, H, (void*)Y2,
                                           2048, 512, 2);
    ln_rows<0><<<(int)(Tc / 4), 256, 0, stream>>>(Y2, g2, be2, nullptr,
                                                  (float*)d_out + t0 * 512);
  }
}

// Round 4
// 829.647 us; speedup vs baseline: 1.1911x; 1.1911x over previous
//
#include <hip/hip_runtime.h>

typedef __attribute__((ext_vector_type(8))) short bf16x8;
typedef __attribute__((ext_vector_type(4))) float f32x4;

__device__ __forceinline__ short f2b(float f) {
  unsigned u = __builtin_bit_cast(unsigned, f);
  unsigned r = (u + 0x7FFFu + ((u >> 16) & 1u)) >> 16;
  return (short)r;
}
__device__ __forceinline__ float b2f(short s) {
  unsigned u = ((unsigned)(unsigned short)s) << 16;
  return __builtin_bit_cast(float, u);
}

__device__ __forceinline__ void gload16(const void* g, void* l) {
  __builtin_amdgcn_global_load_lds(
      (const __attribute__((address_space(1))) void*)g,
      (__attribute__((address_space(3))) void*)l, 16, 0, 0);
}

// tanh-form GELU: |err| vs erf-GELU < ~5e-4, far under bf16 rounding.
__device__ __forceinline__ float gelu_f(float v) {
  float u = v * (0.7978845608f + 0.0356774081f * v * v);
  float a = fabsf(u);
  float e = __expf(-2.f * a);
  float t = (1.f - e) * __builtin_amdgcn_rcpf(1.f + e);
  t = (u < 0.f) ? -t : t;
  return 0.5f * v * (1.f + t);
}

// ---------------- packing kernels ----------------
__global__ void cvt_bf16_vec(const float* __restrict__ src, short* __restrict__ dst, long n) {
  long i = ((long)blockIdx.x * 256 + threadIdx.x) * 8;
  if (i >= n) return;
  f32x4 a = *(const f32x4*)(src + i);
  f32x4 b = *(const f32x4*)(src + i + 4);
  bf16x8 o;
#pragma unroll
  for (int j = 0; j < 4; j++) o[j] = f2b(a[j]);
#pragma unroll
  for (int j = 0; j < 4; j++) o[j + 4] = f2b(b[j]);
  *(bf16x8*)(dst + i) = o;
}

// dst[n][k] = bf16(src[k][n]); both sides coalesced via 32x33 LDS tile.
__global__ void transpose_cvt_t(const float* __restrict__ src, short* __restrict__ dst,
                                int K, int N) {
  __shared__ float tile[32][33];
  const int n0 = blockIdx.x * 32, k0 = blockIdx.y * 32;
  const int j = threadIdx.x & 31, i0 = threadIdx.x >> 5;
#pragma unroll
  for (int r = 0; r < 4; r++) {
    int i = i0 + r * 8;
    tile[i][j] = src[(long)(k0 + i) * N + n0 + j];
  }
  __syncthreads();
#pragma unroll
  for (int r = 0; r < 4; r++) {
    int i = i0 + r * 8;
    dst[(long)(n0 + i) * K + k0 + j] = f2b(tile[j][i]);
  }
}

__global__ void pack_bias3(const float* __restrict__ b0, const float* __restrict__ b1,
                           const float* __restrict__ b2, float* __restrict__ out) {
  int t = blockIdx.x * 256 + threadIdx.x;
  if (t >= 1536) return;
  out[t] = (t < 512) ? b0[t] : ((t < 1024) ? b1[t - 512] : b2[t - 1024]);
}

// ---------------- GEMM: C = A[M][K] @ Bt[N][K]^T  (both bf16) ----------------
// 128x128 tile, BK=32, m97 structure. 1D grid with XCD-bijective swizzle,
// n-fastest tile order (gxN = tiles along N).
// EPI 0: out bf16 = v+bias          (QKV)
// EPI 1: out bf16 = gelu(v+bias)    (fc1)
// EPI 2: out f32  = v+bias+resF     (attn proj + x residual, f32 residual)
// EPI 3: out f32  = v+bias+resB     (fc2 + h residual, bf16 residual)
template <int EPI>
__global__ __launch_bounds__(256, 4) void gemm_bt(
    const short* __restrict__ A, const short* __restrict__ Bt,
    const float* __restrict__ bias, const float* __restrict__ resF,
    const short* __restrict__ resB, void* __restrict__ Cout, int K, int ldc, int gxN) {
  __shared__ short As[128 * 32];
  __shared__ short Bs[128 * 32];
  const int t = threadIdx.x;
  const int w = t >> 6, lane = t & 63;
  const int lr = lane & 15, lg = lane >> 4;

  const int nwg = gridDim.x;
  const int orig = blockIdx.x;
  const int q = nwg >> 3, r = nwg & 7, xcd = orig & 7, idx = orig >> 3;
  const int swz = (xcd < r ? xcd * (q + 1) : r * (q + 1) + (xcd - r) * q) + idx;
  const long m0 = (long)(swz / gxN) * 128;
  const int n0 = (swz % gxN) * 128;

  const int wm = (w >> 1) * 64, wn = (w & 1) * 64;

  f32x4 acc[4][4];
#pragma unroll
  for (int i = 0; i < 4; i++)
#pragma unroll
    for (int j = 0; j < 4; j++) acc[i][j] = f32x4{0.f, 0.f, 0.f, 0.f};

  const int r0 = t >> 2;
  const int kc0 = (t & 3) * 8;
  const short* Ag = A + m0 * K + (long)r0 * K + kc0;
  const short* Bg = Bt + n0 * (long)K + (long)r0 * K + kc0;

  for (int kt = 0; kt < K; kt += 32) {
    gload16(Ag + kt, As + t * 8);
    gload16(Ag + (long)64 * K + kt, As + t * 8 + 2048);
    gload16(Bg + kt, Bs + t * 8);
    gload16(Bg + (long)64 * K + kt, Bs + t * 8 + 2048);
    __syncthreads();
    bf16x8 a[4], b[4];
#pragma unroll
    for (int mi = 0; mi < 4; mi++)
      a[mi] = *(const bf16x8*)(As + (wm + mi * 16 + lr) * 32 + lg * 8);
#pragma unroll
    for (int nj = 0; nj < 4; nj++)
      b[nj] = *(const bf16x8*)(Bs + (wn + nj * 16 + lr) * 32 + lg * 8);
#pragma unroll
    for (int mi = 0; mi < 4; mi++)
#pragma unroll
      for (int nj = 0; nj < 4; nj++)
        acc[mi][nj] =
            __builtin_amdgcn_mfma_f32_16x16x32_bf16(a[mi], b[nj], acc[mi][nj], 0, 0, 0);
    __syncthreads();
  }

  // epilogue: bias hoisted (4 loads), row base hoisted per (mi,i)
  float bv[4];
#pragma unroll
  for (int nj = 0; nj < 4; nj++) bv[nj] = bias[n0 + wn + nj * 16 + lr];

#pragma unroll
  for (int mi = 0; mi < 4; mi++)
#pragma unroll
    for (int i = 0; i < 4; i++) {
      const long row = m0 + wm + mi * 16 + lg * 4 + i;
      const long rb = row * ldc + n0 + wn + lr;
      if (EPI == 0) {
        short* p = (short*)Cout + rb;
#pragma unroll
        for (int nj = 0; nj < 4; nj++) p[nj * 16] = f2b(acc[mi][nj][i] + bv[nj]);
      } else if (EPI == 1) {
        short* p = (short*)Cout + rb;
#pragma unroll
        for (int nj = 0; nj < 4; nj++) p[nj * 16] = f2b(gelu_f(acc[mi][nj][i] + bv[nj]));
      } else if (EPI == 2) {
        float* p = (float*)Cout + rb;
        const float* rp = resF + rb;
#pragma unroll
        for (int nj = 0; nj < 4; nj++) p[nj * 16] = acc[mi][nj][i] + bv[nj] + rp[nj * 16];
      } else {
        float* p = (float*)Cout + rb;
        const short* rp = resB + rb;
#pragma unroll
        for (int nj = 0; nj < 4; nj++)
          p[nj * 16] = acc[mi][nj][i] + bv[nj] + b2f(rp[nj * 16]);
      }
    }
}

// ---------------- windowed attention ----------------
__global__ __launch_bounds__(256, 2) void attn_win(const short* __restrict__ QKV,
                                                   short* __restrict__ AO) {
  __shared__ short Vs[64 * 72];
  __shared__ short Ps[64 * 72];
  const int t = threadIdx.x, w = t >> 6, lane = t & 63;
  const int lr = lane & 15, lg = lane >> 4;
  const long base = (long)blockIdx.x * 64 * 1536;
  const long obase = (long)blockIdx.x * 64 * 512;

  for (int h = 0; h < 8; h++) {
    const int co = h * 64;
#pragma unroll
    for (int it = 0; it < 2; it++) {
      int c = t + it * 256;
      int j = c >> 3, d0 = (c & 7) * 8;
      *(bf16x8*)(Vs + j * 72 + d0) =
          *(const bf16x8*)(QKV + base + (long)j * 1536 + 1024 + co + d0);
    }
    __syncthreads();

    bf16x8 qf[2], kf[4][2];
#pragma unroll
    for (int kb = 0; kb < 2; kb++)
      qf[kb] = *(const bf16x8*)(QKV + base + (long)(w * 16 + lr) * 1536 + co + kb * 32 + lg * 8);
#pragma unroll
    for (int nj = 0; nj < 4; nj++)
#pragma unroll
      for (int kb = 0; kb < 2; kb++)
        kf[nj][kb] = *(const bf16x8*)(QKV + base + (long)(nj * 16 + lr) * 1536 + 512 + co +
                                      kb * 32 + lg * 8);

    f32x4 s[4];
#pragma unroll
    for (int nj = 0; nj < 4; nj++) {
      s[nj] = f32x4{0.f, 0.f, 0.f, 0.f};
      s[nj] = __builtin_amdgcn_mfma_f32_16x16x32_bf16(qf[0], kf[nj][0], s[nj], 0, 0, 0);
      s[nj] = __builtin_amdgcn_mfma_f32_16x16x32_bf16(qf[1], kf[nj][1], s[nj], 0, 0, 0);
      s[nj] = s[nj] * 0.125f;
    }

#pragma unroll
    for (int i = 0; i < 4; i++) {
      float mx = fmaxf(fmaxf(s[0][i], s[1][i]), fmaxf(s[2][i], s[3][i]));
#pragma unroll
      for (int off = 1; off < 16; off <<= 1) mx = fmaxf(mx, __shfl_xor(mx, off, 64));
      float sum = 0.f;
#pragma unroll
      for (int nj = 0; nj < 4; nj++) {
        float p = __expf(s[nj][i] - mx);
        s[nj][i] = p;
        sum += p;
      }
#pragma unroll
      for (int off = 1; off < 16; off <<= 1) sum += __shfl_xor(sum, off, 64);
      float inv = 1.f / sum;
#pragma unroll
      for (int nj = 0; nj < 4; nj++) s[nj][i] *= inv;
    }

#pragma unroll
    for (int nj = 0; nj < 4; nj++)
#pragma unroll
      for (int i = 0; i < 4; i++)
        Ps[(w * 16 + lg * 4 + i) * 72 + nj * 16 + lr] = f2b(s[nj][i]);

    bf16x8 pa[2];
#pragma unroll
    for (int kb = 0; kb < 2; kb++)
      pa[kb] = *(const bf16x8*)(Ps + (w * 16 + lr) * 72 + kb * 32 + lg * 8);

    f32x4 o[4];
#pragma unroll
    for (int nb = 0; nb < 4; nb++) o[nb] = f32x4{0.f, 0.f, 0.f, 0.f};
#pragma unroll
    for (int kb = 0; kb < 2; kb++)
#pragma unroll
      for (int nb = 0; nb < 4; nb++) {
        bf16x8 vb;
#pragma unroll
        for (int jj = 0; jj < 8; jj++)
          vb[jj] = Vs[(kb * 32 + lg * 8 + jj) * 72 + nb * 16 + lr];
        o[nb] = __builtin_amdgcn_mfma_f32_16x16x32_bf16(pa[kb], vb, o[nb], 0, 0, 0);
      }

#pragma unroll
    for (int nb = 0; nb < 4; nb++)
#pragma unroll
      for (int i = 0; i < 4; i++)
        AO[obase + (long)(w * 16 + lg * 4 + i) * 512 + co + nb * 16 + lr] = f2b(o[nb][i]);
    __syncthreads();
  }
}

// ---------------- LayerNorm over C=512, one row per wave ----------------
template <int OUTB>
__global__ __launch_bounds__(256, 4) void ln_rows(const float* __restrict__ Y,
                                                  const float* __restrict__ gamma,
                                                  const float* __restrict__ beta,
                                                  short* __restrict__ Hb,
                                                  float* __restrict__ Of) {
  const int w = threadIdx.x >> 6, lane = threadIdx.x & 63;
  const long row = (long)blockIdx.x * 4 + w;
  const float* y = Y + row * 512 + lane * 8;
  f32x4 a = *(const f32x4*)(y);
  f32x4 b = *(const f32x4*)(y + 4);
  float s = a[0] + a[1] + a[2] + a[3] + b[0] + b[1] + b[2] + b[3];
  float s2 = a[0] * a[0] + a[1] * a[1] + a[2] * a[2] + a[3] * a[3] + b[0] * b[0] +
             b[1] * b[1] + b[2] * b[2] + b[3] * b[3];
#pragma unroll
  for (int off = 1; off < 64; off <<= 1) {
    s += __shfl_xor(s, off, 64);
    s2 += __shfl_xor(s2, off, 64);
  }
  float mu = s * (1.f / 512.f);
  float var = s2 * (1.f / 512.f) - mu * mu;
  float rstd = rsqrtf(fmaxf(var, 0.f) + 1e-12f);
  const int c0 = lane * 8;
  f32x4 ga = *(const f32x4*)(gamma + c0), gb = *(const f32x4*)(gamma + c0 + 4);
  f32x4 ba = *(const f32x4*)(beta + c0), bb = *(const f32x4*)(beta + c0 + 4);
  if (OUTB) {
    bf16x8 o;
#pragma unroll
    for (int j = 0; j < 4; j++) o[j] = f2b(ga[j] * ((a[j] - mu) * rstd) + ba[j]);
#pragma unroll
    for (int j = 0; j < 4; j++) o[j + 4] = f2b(gb[j] * ((b[j] - mu) * rstd) + bb[j]);
    *(bf16x8*)(Hb + row * 512 + c0) = o;
  } else {
    f32x4 o0, o1;
#pragma unroll
    for (int j = 0; j < 4; j++) o0[j] = ga[j] * ((a[j] - mu) * rstd) + ba[j];
#pragma unroll
    for (int j = 0; j < 4; j++) o1[j] = gb[j] * ((b[j] - mu) * rstd) + bb[j];
    *(f32x4*)(Of + row * 512 + c0) = o0;
    *(f32x4*)(Of + row * 512 + c0 + 4) = o1;
  }
}

// ---------------- driver ----------------
extern "C" void kernel_launch(void* const* d_in, const int* in_sizes, int n_in,
                              void* d_out, int out_size, void* d_ws, size_t ws_size,
                              hipStream_t stream) {
  (void)in_sizes; (void)n_in; (void)out_size;
  const float* x = (const float*)d_in[0];
  const float* wq = (const float*)d_in[1];
  const float* bq = (const float*)d_in[2];
  const float* wk = (const float*)d_in[3];
  const float* bk = (const float*)d_in[4];
  const float* wv = (const float*)d_in[5];
  const float* bv = (const float*)d_in[6];
  const float* wo = (const float*)d_in[7];
  const float* bo = (const float*)d_in[8];
  const float* g1 = (const float*)d_in[9];
  const float* be1 = (const float*)d_in[10];
  const float* wfc1 = (const float*)d_in[11];
  const float* bfc1 = (const float*)d_in[12];
  const float* wfc2 = (const float*)d_in[13];
  const float* bfc2 = (const float*)d_in[14];
  const float* g2 = (const float*)d_in[15];
  const float* be2 = (const float*)d_in[16];

  const long T = 65536;
  char* ws = (char*)d_ws;

  // ---- weights at offset 0 (~6.3 MiB) ----
  short* WQKVT = (short*)(ws);                 // [1536][512]
  short* WOT = WQKVT + 1536 * 512;             // [512][512]
  short* WFC1T = WOT + 512 * 512;              // [2048][512]
  short* WFC2T = WFC1T + 2048 * 512;           // [512][2048]
  float* BQKV = (float*)(WFC2T + 512 * 2048);  // [1536]
  size_t woff = ((size_t)((char*)(BQKV + 1536) - ws) + 255) & ~(size_t)255;

  // ---- adaptive chunking (Tc multiple of 128) ----
  size_t avail = (ws_size > woff) ? (ws_size - woff) : 0;
  long Tc = T;
  while (Tc > 128 && (size_t)Tc * 7168 > avail) Tc >>= 1;
  const long nch = T / Tc;

  char* R0 = ws + woff;               // QKV bf16 [Tc][1536] / Y1 f32 / FF1 bf16 [Tc][2048]
  char* R1 = R0 + (size_t)Tc * 4096;  // XB bf16 / AO bf16 / Y2 f32
  char* R2 = R1 + (size_t)Tc * 2048;  // H bf16

  short* QKV = (short*)R0;
  float* Y1 = (float*)R0;
  short* FF1 = (short*)R0;
  short* XB = (short*)R1;
  short* AO = (short*)R1;
  float* Y2 = (float*)R1;
  short* H = (short*)R2;

  // ---- pack weights (tiled transposes, both sides coalesced) ----
  transpose_cvt_t<<<dim3(16, 16), 256, 0, stream>>>(wq, WQKVT, 512, 512);
  transpose_cvt_t<<<dim3(16, 16), 256, 0, stream>>>(wk, WQKVT + 512 * 512, 512, 512);
  transpose_cvt_t<<<dim3(16, 16), 256, 0, stream>>>(wv, WQKVT + 1024 * 512, 512, 512);
  transpose_cvt_t<<<dim3(16, 16), 256, 0, stream>>>(wo, WOT, 512, 512);
  transpose_cvt_t<<<dim3(64, 16), 256, 0, stream>>>(wfc1, WFC1T, 512, 2048);
  transpose_cvt_t<<<dim3(16, 64), 256, 0, stream>>>(wfc2, WFC2T, 2048, 512);
  pack_bias3<<<6, 256, 0, stream>>>(bq, bk, bv, BQKV);

  for (long c = 0; c < nch; c++) {
    const long t0 = c * Tc;
    const int mb = (int)(Tc / 128);
    cvt_bf16_vec<<<(int)(Tc / 4), 256, 0, stream>>>(x + t0 * 512, XB, Tc * 512);
    gemm_bt<0><<<mb * 12, 256, 0, stream>>>(XB, WQKVT, BQKV, nullptr, nullptr,
                                            (void*)QKV, 512, 1536, 12);
    attn_win<<<(int)(Tc / 64), 256, 0, stream>>>(QKV, AO);
    gemm_bt<2><<<mb * 4, 256, 0, stream>>>(AO, WOT, bo, x + t0 * 512, nullptr,
                                           (void*)Y1, 512, 512, 4);
    ln_rows<1><<<(int)(Tc / 4), 256, 0, stream>>>(Y1, g1, be1, H, nullptr);
    gemm_bt<1><<<mb * 16, 256, 0, stream>>>(H, WFC1T, bfc1, nullptr, nullptr,
                                            (void*)FF1, 512, 2048, 16);
    gemm_bt<3><<<mb * 4, 256, 0, stream>>>(FF1, WFC2T, bfc2, nullptr, H, (void*)Y2,
                                           2048, 512, 4);
    ln_rows<0><<<(int)(Tc / 4), 256, 0, stream>>>(Y2, g2, be2, nullptr,
                                                  (float*)d_out + t0 * 512);
  }
}

// Round 5
// 825.613 us; speedup vs baseline: 1.1969x; 1.0049x over previous
//
#include <hip/hip_runtime.h>

typedef __attribute__((ext_vector_type(8))) short bf16x8;
typedef __attribute__((ext_vector_type(4))) float f32x4;

__device__ __forceinline__ short f2b(float f) {
  unsigned u = __builtin_bit_cast(unsigned, f);
  unsigned r = (u + 0x7FFFu + ((u >> 16) & 1u)) >> 16;
  return (short)r;
}
__device__ __forceinline__ float b2f(short s) {
  unsigned u = ((unsigned)(unsigned short)s) << 16;
  return __builtin_bit_cast(float, u);
}

__device__ __forceinline__ void gload16(const void* g, void* l) {
  __builtin_amdgcn_global_load_lds(
      (const __attribute__((address_space(1))) void*)g,
      (__attribute__((address_space(3))) void*)l, 16, 0, 0);
}

// tanh-form GELU: |err| vs erf-GELU < ~5e-4, far under bf16 rounding.
__device__ __forceinline__ float gelu_f(float v) {
  float u = v * (0.7978845608f + 0.0356774081f * v * v);
  float a = fabsf(u);
  float e = __expf(-2.f * a);
  float t = (1.f - e) * __builtin_amdgcn_rcpf(1.f + e);
  t = (u < 0.f) ? -t : t;
  return 0.5f * v * (1.f + t);
}

// ---------------- packing kernels ----------------
__global__ void cvt_bf16_vec(const float* __restrict__ src, short* __restrict__ dst, long n) {
  long i = ((long)blockIdx.x * 256 + threadIdx.x) * 8;
  if (i >= n) return;
  f32x4 a = *(const f32x4*)(src + i);
  f32x4 b = *(const f32x4*)(src + i + 4);
  bf16x8 o;
#pragma unroll
  for (int j = 0; j < 4; j++) o[j] = f2b(a[j]);
#pragma unroll
  for (int j = 0; j < 4; j++) o[j + 4] = f2b(b[j]);
  *(bf16x8*)(dst + i) = o;
}

// dst[n][k] = bf16(src[k][n]); both sides coalesced via 32x33 LDS tile.
__global__ void transpose_cvt_t(const float* __restrict__ src, short* __restrict__ dst,
                                int K, int N) {
  __shared__ float tile[32][33];
  const int n0 = blockIdx.x * 32, k0 = blockIdx.y * 32;
  const int j = threadIdx.x & 31, i0 = threadIdx.x >> 5;
#pragma unroll
  for (int r = 0; r < 4; r++) {
    int i = i0 + r * 8;
    tile[i][j] = src[(long)(k0 + i) * N + n0 + j];
  }
  __syncthreads();
#pragma unroll
  for (int r = 0; r < 4; r++) {
    int i = i0 + r * 8;
    dst[(long)(n0 + i) * K + k0 + j] = f2b(tile[j][i]);
  }
}

__global__ void pack_bias3(const float* __restrict__ b0, const float* __restrict__ b1,
                           const float* __restrict__ b2, float* __restrict__ out) {
  int t = blockIdx.x * 256 + threadIdx.x;
  if (t >= 1536) return;
  out[t] = (t < 512) ? b0[t] : ((t < 1024) ? b1[t - 512] : b2[t - 1024]);
}

// ---------------- GEMM: C = A[M][K] @ Bt[N][K]^T  (both bf16) ----------------
// 128x128 tile, BK=32. 3-buffer LDS ring (48 KiB), stage distance 2,
// counted s_waitcnt vmcnt(4) (never 0 in-loop), ONE barrier per K-tile.
// Staging target buf[(kt+2)%3] is never the buffer being read -> race-free.
// 1D grid with XCD-bijective swizzle, n-fastest (gxN = tiles along N).
// EPI 0: out bf16 = v+bias          (QKV)
// EPI 1: out bf16 = gelu(v+bias)    (fc1)
// EPI 2: out f32  = v+bias+resF     (attn proj + x residual, f32 residual)
// EPI 3: out f32  = v+bias+resB     (fc2 + h residual, bf16 residual)
template <int EPI>
__global__ __launch_bounds__(256, 3) void gemm_bt(
    const short* __restrict__ A, const short* __restrict__ Bt,
    const float* __restrict__ bias, const float* __restrict__ resF,
    const short* __restrict__ resB, void* __restrict__ Cout, int K, int ldc, int gxN) {
  __shared__ short lds[3 * 8192];  // per buffer: A 4096 shorts | B 4096 shorts
  const int t = threadIdx.x;
  const int w = t >> 6, lane = t & 63;
  const int lr = lane & 15, lg = lane >> 4;

  const int nwg = gridDim.x;
  const int orig = blockIdx.x;
  const int q = nwg >> 3, r = nwg & 7, xcd = orig & 7, idx = orig >> 3;
  const int swz = (xcd < r ? xcd * (q + 1) : r * (q + 1) + (xcd - r) * q) + idx;
  const long m0 = (long)(swz / gxN) * 128;
  const int n0 = (swz % gxN) * 128;

  const int wm = (w >> 1) * 64, wn = (w & 1) * 64;

  f32x4 acc[4][4];
#pragma unroll
  for (int i = 0; i < 4; i++)
#pragma unroll
    for (int j = 0; j < 4; j++) acc[i][j] = f32x4{0.f, 0.f, 0.f, 0.f};

  const int r0 = t >> 2;
  const int kc0 = (t & 3) * 8;
  const short* Ag = A + (m0 + r0) * (long)K + kc0;
  const short* Bg = Bt + ((long)n0 + r0) * K + kc0;
  const long half = (long)64 * K;

#define STAGE(b, kt)                                   \
  {                                                    \
    short* d = lds + (b) * 8192 + t * 8;               \
    gload16(Ag + (long)(kt) * 32, d);                  \
    gload16(Ag + half + (long)(kt) * 32, d + 2048);    \
    gload16(Bg + (long)(kt) * 32, d + 4096);           \
    gload16(Bg + half + (long)(kt) * 32, d + 6144);    \
  }

  const int NKT = K >> 5;
  STAGE(0, 0)
  STAGE(1, 1)

  const int aoff = (wm + lr) * 32 + lg * 8;
  const int boff = 4096 + (wn + lr) * 32 + lg * 8;

  int cb = 0, sb = 2;
  for (int kt = 0; kt < NKT - 1; ++kt) {
    // tile kt's 4 loads are the oldest outstanding; keep kt+1's 4 in flight.
    asm volatile("s_waitcnt vmcnt(4)" ::: "memory");
    __builtin_amdgcn_sched_barrier(0);
    __builtin_amdgcn_s_barrier();
    __builtin_amdgcn_sched_barrier(0);
    if (kt + 2 < NKT) STAGE(sb, kt + 2)
    const short* Lb = lds + cb * 8192;
    bf16x8 a[4], b[4];
#pragma unroll
    for (int mi = 0; mi < 4; mi++) a[mi] = *(const bf16x8*)(Lb + aoff + mi * 512);
#pragma unroll
    for (int nj = 0; nj < 4; nj++) b[nj] = *(const bf16x8*)(Lb + boff + nj * 512);
#pragma unroll
    for (int mi = 0; mi < 4; mi++)
#pragma unroll
      for (int nj = 0; nj < 4; nj++)
        acc[mi][nj] =
            __builtin_amdgcn_mfma_f32_16x16x32_bf16(a[mi], b[nj], acc[mi][nj], 0, 0, 0);
    cb = (cb == 2) ? 0 : cb + 1;
    sb = (sb == 2) ? 0 : sb + 1;
  }
  // peeled last tile: full drain allowed here
  {
    asm volatile("s_waitcnt vmcnt(0)" ::: "memory");
    __builtin_amdgcn_sched_barrier(0);
    __builtin_amdgcn_s_barrier();
    __builtin_amdgcn_sched_barrier(0);
    const short* Lb = lds + cb * 8192;
    bf16x8 a[4], b[4];
#pragma unroll
    for (int mi = 0; mi < 4; mi++) a[mi] = *(const bf16x8*)(Lb + aoff + mi * 512);
#pragma unroll
    for (int nj = 0; nj < 4; nj++) b[nj] = *(const bf16x8*)(Lb + boff + nj * 512);
#pragma unroll
    for (int mi = 0; mi < 4; mi++)
#pragma unroll
      for (int nj = 0; nj < 4; nj++)
        acc[mi][nj] =
            __builtin_amdgcn_mfma_f32_16x16x32_bf16(a[mi], b[nj], acc[mi][nj], 0, 0, 0);
  }
#undef STAGE

  // epilogue: bias hoisted (4 loads), row base hoisted per (mi,i)
  float bv[4];
#pragma unroll
  for (int nj = 0; nj < 4; nj++) bv[nj] = bias[n0 + wn + nj * 16 + lr];

#pragma unroll
  for (int mi = 0; mi < 4; mi++)
#pragma unroll
    for (int i = 0; i < 4; i++) {
      const long row = m0 + wm + mi * 16 + lg * 4 + i;
      const long rb = row * ldc + n0 + wn + lr;
      if (EPI == 0) {
        short* p = (short*)Cout + rb;
#pragma unroll
        for (int nj = 0; nj < 4; nj++) p[nj * 16] = f2b(acc[mi][nj][i] + bv[nj]);
      } else if (EPI == 1) {
        short* p = (short*)Cout + rb;
#pragma unroll
        for (int nj = 0; nj < 4; nj++) p[nj * 16] = f2b(gelu_f(acc[mi][nj][i] + bv[nj]));
      } else if (EPI == 2) {
        float* p = (float*)Cout + rb;
        const float* rp = resF + rb;
#pragma unroll
        for (int nj = 0; nj < 4; nj++) p[nj * 16] = acc[mi][nj][i] + bv[nj] + rp[nj * 16];
      } else {
        float* p = (float*)Cout + rb;
        const short* rp = resB + rb;
#pragma unroll
        for (int nj = 0; nj < 4; nj++)
          p[nj * 16] = acc[mi][nj][i] + bv[nj] + b2f(rp[nj * 16]);
      }
    }
}

// ---------------- windowed attention ----------------
__global__ __launch_bounds__(256, 2) void attn_win(const short* __restrict__ QKV,
                                                   short* __restrict__ AO) {
  __shared__ short Vs[64 * 72];
  __shared__ short Ps[64 * 72];
  const int t = threadIdx.x, w = t >> 6, lane = t & 63;
  const int lr = lane & 15, lg = lane >> 4;
  const long base = (long)blockIdx.x * 64 * 1536;
  const long obase = (long)blockIdx.x * 64 * 512;

  for (int h = 0; h < 8; h++) {
    const int co = h * 64;
#pragma unroll
    for (int it = 0; it < 2; it++) {
      int c = t + it * 256;
      int j = c >> 3, d0 = (c & 7) * 8;
      *(bf16x8*)(Vs + j * 72 + d0) =
          *(const bf16x8*)(QKV + base + (long)j * 1536 + 1024 + co + d0);
    }
    __syncthreads();

    bf16x8 qf[2], kf[4][2];
#pragma unroll
    for (int kb = 0; kb < 2; kb++)
      qf[kb] = *(const bf16x8*)(QKV + base + (long)(w * 16 + lr) * 1536 + co + kb * 32 + lg * 8);
#pragma unroll
    for (int nj = 0; nj < 4; nj++)
#pragma unroll
      for (int kb = 0; kb < 2; kb++)
        kf[nj][kb] = *(const bf16x8*)(QKV + base + (long)(nj * 16 + lr) * 1536 + 512 + co +
                                      kb * 32 + lg * 8);

    f32x4 s[4];
#pragma unroll
    for (int nj = 0; nj < 4; nj++) {
      s[nj] = f32x4{0.f, 0.f, 0.f, 0.f};
      s[nj] = __builtin_amdgcn_mfma_f32_16x16x32_bf16(qf[0], kf[nj][0], s[nj], 0, 0, 0);
      s[nj] = __builtin_amdgcn_mfma_f32_16x16x32_bf16(qf[1], kf[nj][1], s[nj], 0, 0, 0);
      s[nj] = s[nj] * 0.125f;
    }

#pragma unroll
    for (int i = 0; i < 4; i++) {
      float mx = fmaxf(fmaxf(s[0][i], s[1][i]), fmaxf(s[2][i], s[3][i]));
#pragma unroll
      for (int off = 1; off < 16; off <<= 1) mx = fmaxf(mx, __shfl_xor(mx, off, 64));
      float sum = 0.f;
#pragma unroll
      for (int nj = 0; nj < 4; nj++) {
        float p = __expf(s[nj][i] - mx);
        s[nj][i] = p;
        sum += p;
      }
#pragma unroll
      for (int off = 1; off < 16; off <<= 1) sum += __shfl_xor(sum, off, 64);
      float inv = 1.f / sum;
#pragma unroll
      for (int nj = 0; nj < 4; nj++) s[nj][i] *= inv;
    }

#pragma unroll
    for (int nj = 0; nj < 4; nj++)
#pragma unroll
      for (int i = 0; i < 4; i++)
        Ps[(w * 16 + lg * 4 + i) * 72 + nj * 16 + lr] = f2b(s[nj][i]);

    bf16x8 pa[2];
#pragma unroll
    for (int kb = 0; kb < 2; kb++)
      pa[kb] = *(const bf16x8*)(Ps + (w * 16 + lr) * 72 + kb * 32 + lg * 8);

    f32x4 o[4];
#pragma unroll
    for (int nb = 0; nb < 4; nb++) o[nb] = f32x4{0.f, 0.f, 0.f, 0.f};
#pragma unroll
    for (int kb = 0; kb < 2; kb++)
#pragma unroll
      for (int nb = 0; nb < 4; nb++) {
        bf16x8 vb;
#pragma unroll
        for (int jj = 0; jj < 8; jj++)
          vb[jj] = Vs[(kb * 32 + lg * 8 + jj) * 72 + nb * 16 + lr];
        o[nb] = __builtin_amdgcn_mfma_f32_16x16x32_bf16(pa[kb], vb, o[nb], 0, 0, 0);
      }

#pragma unroll
    for (int nb = 0; nb < 4; nb++)
#pragma unroll
      for (int i = 0; i < 4; i++)
        AO[obase + (long)(w * 16 + lg * 4 + i) * 512 + co + nb * 16 + lr] = f2b(o[nb][i]);
    __syncthreads();
  }
}

// ---------------- LayerNorm over C=512, one row per wave ----------------
template <int OUTB>
__global__ __launch_bounds__(256, 4) void ln_rows(const float* __restrict__ Y,
                                                  const float* __restrict__ gamma,
                                                  const float* __restrict__ beta,
                                                  short* __restrict__ Hb,
                                                  float* __restrict__ Of) {
  const int w = threadIdx.x >> 6, lane = threadIdx.x & 63;
  const long row = (long)blockIdx.x * 4 + w;
  const float* y = Y + row * 512 + lane * 8;
  f32x4 a = *(const f32x4*)(y);
  f32x4 b = *(const f32x4*)(y + 4);
  float s = a[0] + a[1] + a[2] + a[3] + b[0] + b[1] + b[2] + b[3];
  float s2 = a[0] * a[0] + a[1] * a[1] + a[2] * a[2] + a[3] * a[3] + b[0] * b[0] +
             b[1] * b[1] + b[2] * b[2] + b[3] * b[3];
#pragma unroll
  for (int off = 1; off < 64; off <<= 1) {
    s += __shfl_xor(s, off, 64);
    s2 += __shfl_xor(s2, off, 64);
  }
  float mu = s * (1.f / 512.f);
  float var = s2 * (1.f / 512.f) - mu * mu;
  float rstd = rsqrtf(fmaxf(var, 0.f) + 1e-12f);
  const int c0 = lane * 8;
  f32x4 ga = *(const f32x4*)(gamma + c0), gb = *(const f32x4*)(gamma + c0 + 4);
  f32x4 ba = *(const f32x4*)(beta + c0), bb = *(const f32x4*)(beta + c0 + 4);
  if (OUTB) {
    bf16x8 o;
#pragma unroll
    for (int j = 0; j < 4; j++) o[j] = f2b(ga[j] * ((a[j] - mu) * rstd) + ba[j]);
#pragma unroll
    for (int j = 0; j < 4; j++) o[j + 4] = f2b(gb[j] * ((b[j] - mu) * rstd) + bb[j]);
    *(bf16x8*)(Hb + row * 512 + c0) = o;
  } else {
    f32x4 o0, o1;
#pragma unroll
    for (int j = 0; j < 4; j++) o0[j] = ga[j] * ((a[j] - mu) * rstd) + ba[j];
#pragma unroll
    for (int j = 0; j < 4; j++) o1[j] = gb[j] * ((b[j] - mu) * rstd) + bb[j];
    *(f32x4*)(Of + row * 512 + c0) = o0;
    *(f32x4*)(Of + row * 512 + c0 + 4) = o1;
  }
}

// ---------------- driver ----------------
extern "C" void kernel_launch(void* const* d_in, const int* in_sizes, int n_in,
                              void* d_out, int out_size, void* d_ws, size_t ws_size,
                              hipStream_t stream) {
  (void)in_sizes; (void)n_in; (void)out_size;
  const float* x = (const float*)d_in[0];
  const float* wq = (const float*)d_in[1];
  const float* bq = (const float*)d_in[2];
  const float* wk = (const float*)d_in[3];
  const float* bk = (const float*)d_in[4];
  const float* wv = (const float*)d_in[5];
  const float* bv = (const float*)d_in[6];
  const float* wo = (const float*)d_in[7];
  const float* bo = (const float*)d_in[8];
  const float* g1 = (const float*)d_in[9];
  const float* be1 = (const float*)d_in[10];
  const float* wfc1 = (const float*)d_in[11];
  const float* bfc1 = (const float*)d_in[12];
  const float* wfc2 = (const float*)d_in[13];
  const float* bfc2 = (const float*)d_in[14];
  const float* g2 = (const float*)d_in[15];
  const float* be2 = (const float*)d_in[16];

  const long T = 65536;
  char* ws = (char*)d_ws;

  // ---- weights at offset 0 (~6.3 MiB) ----
  short* WQKVT = (short*)(ws);                 // [1536][512]
  short* WOT = WQKVT + 1536 * 512;             // [512][512]
  short* WFC1T = WOT + 512 * 512;              // [2048][512]
  short* WFC2T = WFC1T + 2048 * 512;           // [512][2048]
  float* BQKV = (float*)(WFC2T + 512 * 2048);  // [1536]
  size_t woff = ((size_t)((char*)(BQKV + 1536) - ws) + 255) & ~(size_t)255;

  // ---- adaptive chunking (Tc multiple of 128) ----
  size_t avail = (ws_size > woff) ? (ws_size - woff) : 0;
  long Tc = T;
  while (Tc > 128 && (size_t)Tc * 7168 > avail) Tc >>= 1;
  const long nch = T / Tc;

  char* R0 = ws + woff;               // QKV bf16 [Tc][1536] / Y1 f32 / FF1 bf16 [Tc][2048]
  char* R1 = R0 + (size_t)Tc * 4096;  // XB bf16 / AO bf16 / Y2 f32
  char* R2 = R1 + (size_t)Tc * 2048;  // H bf16

  short* QKV = (short*)R0;
  float* Y1 = (float*)R0;
  short* FF1 = (short*)R0;
  short* XB = (short*)R1;
  short* AO = (short*)R1;
  float* Y2 = (float*)R1;
  short* H = (short*)R2;

  // ---- pack weights (tiled transposes, both sides coalesced) ----
  transpose_cvt_t<<<dim3(16, 16), 256, 0, stream>>>(wq, WQKVT, 512, 512);
  transpose_cvt_t<<<dim3(16, 16), 256, 0, stream>>>(wk, WQKVT + 512 * 512, 512, 512);
  transpose_cvt_t<<<dim3(16, 16), 256, 0, stream>>>(wv, WQKVT + 1024 * 512, 512, 512);
  transpose_cvt_t<<<dim3(16, 16), 256, 0, stream>>>(wo, WOT, 512, 512);
  transpose_cvt_t<<<dim3(64, 16), 256, 0, stream>>>(wfc1, WFC1T, 512, 2048);
  transpose_cvt_t<<<dim3(16, 64), 256, 0, stream>>>(wfc2, WFC2T, 2048, 512);
  pack_bias3<<<6, 256, 0, stream>>>(bq, bk, bv, BQKV);

  for (long c = 0; c < nch; c++) {
    const long t0 = c * Tc;
    const int mb = (int)(Tc / 128);
    cvt_bf16_vec<<<(int)(Tc / 4), 256, 0, stream>>>(x + t0 * 512, XB, Tc * 512);
    gemm_bt<0><<<mb * 12, 256, 0, stream>>>(XB, WQKVT, BQKV, nullptr, nullptr,
                                            (void*)QKV, 512, 1536, 12);
    attn_win<<<(int)(Tc / 64), 256, 0, stream>>>(QKV, AO);
    gemm_bt<2><<<mb * 4, 256, 0, stream>>>(AO, WOT, bo, x + t0 * 512, nullptr,
                                           (void*)Y1, 512, 512, 4);
    ln_rows<1><<<(int)(Tc / 4), 256, 0, stream>>>(Y1, g1, be1, H, nullptr);
    gemm_bt<1><<<mb * 16, 256, 0, stream>>>(H, WFC1T, bfc1, nullptr, nullptr,
                                            (void*)FF1, 512, 2048, 16);
    gemm_bt<3><<<mb * 4, 256, 0, stream>>>(FF1, WFC2T, bfc2, nullptr, H, (void*)Y2,
                                           2048, 512, 4);
    ln_rows<0><<<(int)(Tc / 4), 256, 0, stream>>>(Y2, g2, be2, nullptr,
                                                  (float*)d_out + t0 * 512);
  }
}